// Round 13
// baseline (411.023 us; speedup 1.0000x reference)
//
#include <hip/hip_runtime.h>
#include <hip/hip_fp16.h>
#include <math.h>

#define N 1024
#define BATCH 16
#define CH 3
#define BC 48
#define OUTHW 224
#define KSCALE (1024.0f / 224.0f)
#define SCALE  (224.0f / 1024.0f)
// ---- disjoint workspace layout (byte ranges verified non-overlapping) ----
// A   (half2): [0, 100,859,904)                48 x 525,312 half2 (2.101 MB each)
// T1  (float): [100,859,904, 144,900,096)      48 x 229,376 floats
// slots (int): [144,900,096, 144,908,288)      2048 ints
#define AST    525312                        // half2 per image (513*1024), dense
#define T1BASE 25214976                      // float offset of T1 region
#define T1SZ   (OUTHW * N)                   // 229376 floats per bc
#define SLOTBASE 36225024                    // float offset of slots
#define TWOPI 6.283185307179586f
#define WBAR() __builtin_amdgcn_wave_barrier()

// (ar,ai)*(br,bi) -> (dr,di); safe when d aliases a
#define CMUL(dr, di, ar, ai, br, bi) do {                         \
    float _r = (ar) * (br) - (ai) * (bi);                         \
    float _i = (ar) * (bi) + (ai) * (br);                         \
    (dr) = _r; (di) = _i; } while (0)

// forward DFT-4
#define RADIX4(ar,ai,br,bi,cr,ci,dr,di, o0r,o0i,o1r,o1i,o2r,o2i,o3r,o3i) do { \
    float u0r=(ar)+(cr), u0i=(ai)+(ci);                           \
    float u1r=(ar)-(cr), u1i=(ai)-(ci);                           \
    float u2r=(br)+(dr), u2i=(bi)+(di);                           \
    float u3r=(bi)-(di), u3i=(dr)-(br);                           \
    (o0r)=u0r+u2r; (o0i)=u0i+u2i;                                 \
    (o1r)=u1r+u3r; (o1i)=u1i+u3i;                                 \
    (o2r)=u0r-u2r; (o2i)=u0i-u2i;                                 \
    (o3r)=u1r-u3r; (o3i)=u1i-u3i; } while (0)

// In-register natural-order 16-pt forward DFT (Stockham radix-4 x radix-4).
__device__ __forceinline__ void dft16(float* xr, float* xi) {
  const float W16R[4][4] = {
    {1.f, 1.f, 1.f, 1.f},
    {1.f,  0.9238795325f,  0.7071067812f,  0.3826834324f},
    {1.f,  0.7071067812f,  0.0f,          -0.7071067812f},
    {1.f,  0.3826834324f, -0.7071067812f, -0.9238795325f}};
  const float W16I[4][4] = {
    {0.f, 0.f, 0.f, 0.f},
    {0.f, -0.3826834324f, -0.7071067812f, -0.9238795325f},
    {0.f, -0.7071067812f, -1.0f,          -0.7071067812f},
    {0.f, -0.9238795325f, -0.7071067812f,  0.3826834324f}};
  float tr[16], ti[16];
#pragma unroll
  for (int j = 0; j < 4; ++j) {
    RADIX4(xr[j],xi[j], xr[j+4],xi[j+4], xr[j+8],xi[j+8], xr[j+12],xi[j+12],
           tr[4*j],ti[4*j], tr[4*j+1],ti[4*j+1], tr[4*j+2],ti[4*j+2], tr[4*j+3],ti[4*j+3]);
  }
#pragma unroll
  for (int j = 0; j < 4; ++j) {
    float ar[4], ai_[4];
#pragma unroll
    for (int k = 0; k < 4; ++k) {
      if (j == 0 || k == 0) { ar[k] = tr[j+4*k]; ai_[k] = ti[j+4*k]; }
      else CMUL(ar[k], ai_[k], tr[j+4*k], ti[j+4*k], W16R[j][k], W16I[j][k]);
    }
    RADIX4(ar[0],ai_[0], ar[1],ai_[1], ar[2],ai_[2], ar[3],ai_[3],
           xr[j],xi[j], xr[j+4],xi[j+4], xr[j+8],xi[j+8], xr[j+12],xi[j+12]);
  }
}

// Stage 2 with REGISTER twiddles: W256^{j2*k} from one sincos + 14-CMUL
// recurrence (error ~15 ulp, << fp16 A error). No memory traffic.
__device__ __forceinline__ void stage2_reg(float* xr, float* xi, int j2) {
  float s1, c1;
  __sincosf(-TWOPI * (float)j2 * (1.0f / 256.0f), &s1, &c1);
  float wr = c1, wi = s1;
#pragma unroll
  for (int k = 1; k < 16; ++k) {
    CMUL(xr[k], xi[k], xr[k], xi[k], wr, wi);
    if (k < 15) CMUL(wr, wi, wr, wi, c1, s1);   // w^{k+1}
  }
  dft16(xr, xi);
}

// Register-twiddle stage 3 (shared by both FFT variants):
// W1024^{(l+64m)k} = (W1024^l * W16^m)^k, W16^m compile-time constants.
__device__ __forceinline__ void stage3_reg(float* xr, float* xi, int l) {
  float sl, cl;
  __sincosf(-TWOPI * (float)l * (1.0f / 1024.0f), &sl, &cl);
  const float W16mR[4] = {1.f,  0.9238795325f,  0.7071067812f,  0.3826834324f};
  const float W16mI[4] = {0.f, -0.3826834324f, -0.7071067812f, -0.9238795325f};
#pragma unroll
  for (int m = 0; m < 4; ++m) {        // stage 3 (Ns=256, radix-4), in-place
    float ar[4], ai_[4];
#pragma unroll
    for (int k = 0; k < 4; ++k) { ar[k] = xr[m + 4*k]; ai_[k] = xi[m + 4*k]; }
    float w1r, w1i, w2r, w2i, w3r, w3i;
    CMUL(w1r, w1i, cl, sl, W16mR[m], W16mI[m]);  // W1024^{l+64m}
    CMUL(w2r, w2i, w1r, w1i, w1r, w1i);          // ^2
    CMUL(w3r, w3i, w2r, w2i, w1r, w1i);          // ^3
    CMUL(ar[1], ai_[1], ar[1], ai_[1], w1r, w1i);
    CMUL(ar[2], ai_[2], ar[2], ai_[2], w2r, w2i);
    CMUL(ar[3], ai_[3], ar[3], ai_[3], w3r, w3i);
    RADIX4(ar[0],ai_[0], ar[1],ai_[1], ar[2],ai_[2], ar[3],ai_[3],
           xr[m],xi[m], xr[m+4],xi[m+4], xr[m+8],xi[m+8], xr[m+12],xi[m+12]);
  }
}

// 1-buffer float FFT (R4-proven; used by k_rowfft as the control arm).
__device__ __forceinline__ void wave_fft1024_1buf(float* xr, float* xi,
                                                  float* wb, int l) {
  const int base2 = l + (l >> 4);
  const int j2 = l & 15;
  const int ob = 272 * (l >> 4) + j2;
  dft16(xr, xi);                       // stage 1 (Ns=1)
#pragma unroll
  for (int k = 0; k < 16; ++k) wb[17*l + k] = xr[k];
  WBAR();
#pragma unroll
  for (int k = 0; k < 16; ++k) xr[k] = wb[base2 + 68*k];
  WBAR();
#pragma unroll
  for (int k = 0; k < 16; ++k) wb[17*l + k] = xi[k];
  WBAR();
#pragma unroll
  for (int k = 0; k < 16; ++k) xi[k] = wb[base2 + 68*k];
  WBAR();
  stage2_reg(xr, xi, j2);              // stage 2 (Ns=16)
#pragma unroll
  for (int k = 0; k < 16; ++k) wb[ob + 17*k] = xr[k];
  WBAR();
#pragma unroll
  for (int m = 0; m < 4; ++m)
#pragma unroll
    for (int k = 0; k < 4; ++k) xr[m + 4*k] = wb[base2 + 68*m + 272*k];
  WBAR();
#pragma unroll
  for (int k = 0; k < 16; ++k) wb[ob + 17*k] = xi[k];
  WBAR();
#pragma unroll
  for (int m = 0; m < 4; ++m)
#pragma unroll
    for (int k = 0; k < 4; ++k) xi[m + 4*k] = wb[base2 + 68*m + 272*k];
  WBAR();
  stage3_reg(xr, xi, l);
}

// float2-element 1-buffer FFT (R13 experiment, colfft only): re/im packed in
// one LDS element -> every exchange op is ds_{write,read}_b64. Halves the DS
// op count (128 -> 64) and uses the wider-op throughput advantage (b32 ~44
// B/cy vs b128 ~85 B/cy on this chip). The +17 row padding keeps each b64 op
// at its 4-cycle bank minimum (16 distinct bank-pairs/op). Costs 2x LDS.
__device__ __forceinline__ void wave_fft1024_f2(float* xr, float* xi,
                                                float2* wb2, int l) {
  const int base2 = l + (l >> 4);
  const int j2 = l & 15;
  const int ob = 272 * (l >> 4) + j2;
  dft16(xr, xi);                       // stage 1 (Ns=1)
#pragma unroll
  for (int k = 0; k < 16; ++k) wb2[17*l + k] = make_float2(xr[k], xi[k]);
  WBAR();
#pragma unroll
  for (int k = 0; k < 16; ++k) {
    float2 v = wb2[base2 + 68*k];
    xr[k] = v.x; xi[k] = v.y;
  }
  WBAR();
  stage2_reg(xr, xi, j2);              // stage 2 (Ns=16)
#pragma unroll
  for (int k = 0; k < 16; ++k) wb2[ob + 17*k] = make_float2(xr[k], xi[k]);
  WBAR();
#pragma unroll
  for (int m = 0; m < 4; ++m)
#pragma unroll
    for (int k = 0; k < 4; ++k) {
      float2 v = wb2[base2 + 68*m + 272*k];
      xr[m + 4*k] = v.x; xi[m + 4*k] = v.y;
    }
  WBAR();
  stage3_reg(xr, xi, l);
}

__global__ void k_init(int* __restrict__ slots) {
  int g = blockIdx.x * 256 + threadIdx.x;   // 0..2047
  if (g < 1024) slots[g] = 0x7F800000;      // +inf (min slots, 16 b x 64 slices)
  else          slots[g] = 0;               // 0 (max slots; spec >= 0)
}

// Pass 1 (R12-exact, control arm): 8 waves/block, 16 rows, float 1-buffer FFT,
// Hermitian unpack + transposed staging in two v-halves, XCD swizzle, fp16 A.
__global__ __launch_bounds__(512, 6) void k_rowfft(const float* __restrict__ in,
                                                   __half2* __restrict__ A) {
  __shared__ float lds[8704];          // 8 waves x 1088; overlaid: stg [16][260] x2
  const int t  = threadIdx.x;
  const int w  = t >> 6;               // 0..7
  const int l  = t & 63;
  const int j   = blockIdx.x;
  const int q   = j >> 3;
  const int bc  = (j & 7) * 6 + (q >> 6);   // image 0..47 (XCD swizzle)
  const int h0b = (q & 63) << 4;            // 16 rows per block
  const int r0  = h0b + 2 * w;
  float* wb = lds + w * 1088;
  const float* row0 = in + ((size_t)bc << 20) + ((size_t)r0 << 10);
  const float* row1 = row0 + N;
  float xr[16], xi[16];
  const float sgn = (l & 1) ? -1.0f : 1.0f;   // fftshift sign (-1)^h
#pragma unroll
  for (int k = 0; k < 16; ++k) {
    xr[k] =  sgn * row0[l + 64*k];
    xi[k] = -sgn * row1[l + 64*k];
  }
  wave_fft1024_1buf(xr, xi, wb, l);
  float* stre = lds;                   // [16][260]
  float* stim = lds + 4160;            // [16][260]
  const int rr = t & 15, v0 = t >> 4;
  __half2* Abc = A + (size_t)bc * AST;
#pragma unroll
  for (int h = 0; h < 2; ++h) {
    const int slo = (h == 0) ? 0 : 4;
    const int cnt = (h == 0) ? 4 : 5;
    float par[5], pai[5], pbr[5], pbi[5];
    __syncthreads();
#pragma unroll
    for (int s = 0; s < 16; ++s) wb[l + 64*s] = xr[s];
    WBAR();
#pragma unroll
    for (int u = 0; u < 5; ++u) {
      if (u < cnt) {
        int s = slo + u;
        int i = l + 64*s;
        if (i <= 512) {
          float qr = wb[(N - i) & (N - 1)];
          par[u] = 0.5f * (xr[s] + qr);
          pbi[u] = 0.5f * (qr - xr[s]);
        }
      }
    }
    WBAR();
#pragma unroll
    for (int s = 0; s < 16; ++s) wb[l + 64*s] = xi[s];
    WBAR();
#pragma unroll
    for (int u = 0; u < 5; ++u) {
      if (u < cnt) {
        int s = slo + u;
        int i = l + 64*s;
        if (i <= 512) {
          float qi = wb[(N - i) & (N - 1)];
          pai[u] = 0.5f * (xi[s] - qi);
          pbr[u] = 0.5f * (xi[s] + qi);
        }
      }
    }
    __syncthreads();
#pragma unroll
    for (int u = 0; u < 5; ++u) {
      if (u < cnt) {
        int s = slo + u;
        int i = l + 64*s;
        if (i <= 512) {
          int c = i - 256 * h;
          stre[(2*w)     * 260 + c] = par[u]; stim[(2*w)     * 260 + c] = pai[u];
          stre[(2*w + 1) * 260 + c] = pbr[u]; stim[(2*w + 1) * 260 + c] = pbi[u];
        }
      }
    }
    __syncthreads();
#pragma unroll
    for (int i2 = 0; i2 < 9; ++i2) {
      if (i2 < 8 + h) {
        int v = 256 * h + v0 + 32 * i2;
        if (v <= 512) {
          int c = v - 256 * h;
          Abc[(size_t)v * N + h0b + rr] =
              __floats2half2_rn(stre[rr*260 + c], stim[rr*260 + c]);
        }
      }
    }
  }
}

// Pass 2 (R13 experiment): float2-LDS FFT (b64 exchange ops, 34816 B/block ->
// 16 waves/CU) + spec + sliced minmax atomics + 10-tap fused resize.
__global__ __launch_bounds__(256, 4) void k_colfft(const __half2* __restrict__ A,
                                                   float* __restrict__ WSf,
                                                   int* __restrict__ slots) {
  __shared__ float2 lds2[4352];        // 4 waves x 1088 float2 (34816 B)
  const int t  = threadIdx.x;
  const int w  = t >> 6;
  const int l  = t & 63;
  const int gw = blockIdx.x * 4 + w;   // 0..24623 == BC*513-1 exactly
  const int bc = gw / 513;
  const int sx = gw - bc * 513;
  const int b  = bc / CH;
  float2* wb2 = lds2 + w * 1088;
  float* specf = (float*)wb2;          // float view for spec/resize (first 1024)
  const __half2* src = A + (size_t)bc * AST + ((size_t)sx << 10);
  float xr[16], xi[16];
#pragma unroll
  for (int k = 0; k < 16; ++k) {
    float2 v = __half22float2(src[l + 64*k]);
    xr[k] = v.x; xi[k] = v.y;
  }
  wave_fft1024_f2(xr, xi, wb2, l);
  float lmin = 3.4e38f, lmax = 0.0f;
#pragma unroll
  for (int s = 0; s < 16; ++s) {
    float sp = __logf(1.0f + sqrtf(xr[s]*xr[s] + xi[s]*xi[s]));
    specf[l + 64*s] = sp;              // spec plain-indexed in own buffer
    lmin = fminf(lmin, sp); lmax = fmaxf(lmax, sp);
  }
#pragma unroll
  for (int off = 32; off; off >>= 1) {
    lmin = fminf(lmin, __shfl_xor(lmin, off));
    lmax = fmaxf(lmax, __shfl_xor(lmax, off));
  }
  if (l == 0) {                        // spread over 64 slices/image
    atomicMin(&slots[b * 64 + (sx & 63)],        __float_as_int(lmin));
    atomicMax(&slots[1024 + b * 64 + (sx & 63)], __float_as_int(lmax));
  }
  WBAR();
  float* T1 = WSf + T1BASE + (size_t)bc * T1SZ;
  const bool mir = (sx != 0) && (sx != 512);
#pragma unroll
  for (int obk = 0; obk < 4; ++obk) {
    int oh = l + 64 * obk;
    if (oh < OUTHW) {
      float x = ((float)oh + 0.5f) * KSCALE - 0.5f;
      int jlo = (int)ceilf(x - KSCALE);           // unclamped; window < 10 taps
      float ssum = 0.0f, acc = 0.0f, accm = 0.0f;
#pragma unroll
      for (int u = 0; u < 10; ++u) {
        int jj = jlo + u;
        float wgt = 1.0f - fabsf((float)jj - x) * SCALE;
        wgt = fmaxf(wgt, 0.0f);
        bool valid = (jj >= 0) && (jj <= N - 1);
        if (!valid) wgt = 0.0f;
        int ja = valid ? jj : 0;
        ssum += wgt;
        acc  += wgt * specf[ja];
        accm += wgt * specf[(N - ja) & (N - 1)];
      }
      float inv = 1.0f / ssum;
      T1[(size_t)sx * OUTHW + oh] = acc * inv;
      if (mir) T1[(size_t)(N - sx) * OUTHW + oh] = accm * inv;
    }
  }
}

// Pass 3 (R12-exact): contract v + normalization; direct coalesced T1 reads,
// fixed 10-tap unrolled loop, slot min/max reduction merged in.
__global__ __launch_bounds__(256) void k_resize2(const float* __restrict__ WSf,
                                                 const int* __restrict__ slots,
                                                 float* __restrict__ out) {
  __shared__ float s2[2];
  const int ow = blockIdx.x % OUTHW;
  const int bc = blockIdx.x / OUTHW;
  const int b  = bc / CH;
  const int t  = threadIdx.x;
  if (t < 64) {
    int mn = slots[b * 64 + t];
#pragma unroll
    for (int off = 32; off; off >>= 1) mn = min(mn, __shfl_xor(mn, off));
    if (t == 0) s2[0] = __int_as_float(mn);
  } else if (t < 128) {
    int mx = slots[1024 + b * 64 + (t - 64)];
#pragma unroll
    for (int off = 32; off; off >>= 1) mx = max(mx, __shfl_xor(mx, off));
    if (t == 64) s2[1] = __int_as_float(mx);
  }
  __syncthreads();
  if (t >= OUTHW) return;
  const float mn = s2[0];
  const float mx = s2[1];
  const float inv = 1.0f / (mx - mn + 1e-8f);
  const float* T1 = WSf + T1BASE + (size_t)bc * T1SZ;
  float x = ((float)ow + 0.5f) * KSCALE - 0.5f;
  int jlo = (int)ceilf(x - KSCALE);              // unclamped; window < 10 taps
  float ssum = 0.0f, acc = 0.0f;
#pragma unroll
  for (int u = 0; u < 10; ++u) {
    int jj = jlo + u;
    float wv = 1.0f - fabsf((float)jj - x) * SCALE;
    wv = fmaxf(wv, 0.0f);
    bool valid = (jj >= 0) && (jj <= N - 1);
    if (!valid) wv = 0.0f;
    int ja = valid ? jj : 0;                     // row 0 always valid memory
    ssum += wv;
    acc += wv * T1[(size_t)ja * OUTHW + t];      // coalesced 896B per tap row
  }
  float v = acc / ssum;
  out[((size_t)bc * OUTHW + t) * OUTHW + ow] = (v - mn) * inv;
}

extern "C" void kernel_launch(void* const* d_in, const int* in_sizes, int n_in,
                              void* d_out, int out_size, void* d_ws, size_t ws_size,
                              hipStream_t stream) {
  const float* in = (const float*)d_in[0];
  float* out = (float*)d_out;
  __half2* A = (__half2*)d_ws;                 // dense fp16 A region [0, 100.9MB)
  float* WSf = (float*)d_ws;
  int* slots = (int*)(WSf + SLOTBASE);         // [144.9MB, +8KB)

  k_init<<<8, 256, 0, stream>>>(slots);
  k_rowfft<<<BC * 64, 512, 0, stream>>>(in, A);
  k_colfft<<<(BC * 513) / 4, 256, 0, stream>>>(A, WSf, slots);
  k_resize2<<<BC * OUTHW, 256, 0, stream>>>(WSf, slots, out);
}

// Round 16
// 401.186 us; speedup vs baseline: 1.0245x; 1.0245x over previous
//
#include <hip/hip_runtime.h>
#include <hip/hip_fp16.h>
#include <math.h>

#define N 1024
#define BATCH 16
#define CH 3
#define BC 48
#define OUTHW 224
#define KSCALE (1024.0f / 224.0f)
#define SCALE  (224.0f / 1024.0f)
// ---- disjoint workspace layout (byte ranges verified non-overlapping) ----
// A   (half2): [0, 100,859,904)                48 x 525,312 half2 (2.101 MB each)
// T1  (float): [100,859,904, 144,900,096)      48 x 229,376 floats
// slots (int): [144,900,096, 144,908,288)      2048 ints
#define AST    525312                        // half2 per image (513*1024), dense
#define T1BASE 25214976                      // float offset of T1 region
#define T1SZ   (OUTHW * N)                   // 229376 floats per bc
#define SLOTBASE 36225024                    // float offset of slots
#define TWOPI 6.283185307179586f
#define WBAR() __builtin_amdgcn_wave_barrier()

// (ar,ai)*(br,bi) -> (dr,di); safe when d aliases a
#define CMUL(dr, di, ar, ai, br, bi) do {                         \
    float _r = (ar) * (br) - (ai) * (bi);                         \
    float _i = (ar) * (bi) + (ai) * (br);                         \
    (dr) = _r; (di) = _i; } while (0)

// forward DFT-4
#define RADIX4(ar,ai,br,bi,cr,ci,dr,di, o0r,o0i,o1r,o1i,o2r,o2i,o3r,o3i) do { \
    float u0r=(ar)+(cr), u0i=(ai)+(ci);                           \
    float u1r=(ar)-(cr), u1i=(ai)-(ci);                           \
    float u2r=(br)+(dr), u2i=(bi)+(di);                           \
    float u3r=(bi)-(di), u3i=(dr)-(br);                           \
    (o0r)=u0r+u2r; (o0i)=u0i+u2i;                                 \
    (o1r)=u1r+u3r; (o1i)=u1i+u3i;                                 \
    (o2r)=u0r-u2r; (o2i)=u0i-u2i;                                 \
    (o3r)=u1r-u3r; (o3i)=u1i-u3i; } while (0)

// In-register natural-order 16-pt forward DFT (Stockham radix-4 x radix-4).
__device__ __forceinline__ void dft16(float* xr, float* xi) {
  const float W16R[4][4] = {
    {1.f, 1.f, 1.f, 1.f},
    {1.f,  0.9238795325f,  0.7071067812f,  0.3826834324f},
    {1.f,  0.7071067812f,  0.0f,          -0.7071067812f},
    {1.f,  0.3826834324f, -0.7071067812f, -0.9238795325f}};
  const float W16I[4][4] = {
    {0.f, 0.f, 0.f, 0.f},
    {0.f, -0.3826834324f, -0.7071067812f, -0.9238795325f},
    {0.f, -0.7071067812f, -1.0f,          -0.7071067812f},
    {0.f, -0.9238795325f, -0.7071067812f,  0.3826834324f}};
  float tr[16], ti[16];
#pragma unroll
  for (int j = 0; j < 4; ++j) {
    RADIX4(xr[j],xi[j], xr[j+4],xi[j+4], xr[j+8],xi[j+8], xr[j+12],xi[j+12],
           tr[4*j],ti[4*j], tr[4*j+1],ti[4*j+1], tr[4*j+2],ti[4*j+2], tr[4*j+3],ti[4*j+3]);
  }
#pragma unroll
  for (int j = 0; j < 4; ++j) {
    float ar[4], ai_[4];
#pragma unroll
    for (int k = 0; k < 4; ++k) {
      if (j == 0 || k == 0) { ar[k] = tr[j+4*k]; ai_[k] = ti[j+4*k]; }
      else CMUL(ar[k], ai_[k], tr[j+4*k], ti[j+4*k], W16R[j][k], W16I[j][k]);
    }
    RADIX4(ar[0],ai_[0], ar[1],ai_[1], ar[2],ai_[2], ar[3],ai_[3],
           xr[j],xi[j], xr[j+4],xi[j+4], xr[j+8],xi[j+8], xr[j+12],xi[j+12]);
  }
}

// Stage 2 with REGISTER twiddles: W256^{j2*k} from one sincos + 14-CMUL
// recurrence (error ~15 ulp, << fp16 A error). No memory traffic.
__device__ __forceinline__ void stage2_reg(float* xr, float* xi, int j2) {
  float s1, c1;
  __sincosf(-TWOPI * (float)j2 * (1.0f / 256.0f), &s1, &c1);
  float wr = c1, wi = s1;
#pragma unroll
  for (int k = 1; k < 16; ++k) {
    CMUL(xr[k], xi[k], xr[k], xi[k], wr, wi);
    if (k < 15) CMUL(wr, wi, wr, wi, c1, s1);   // w^{k+1}
  }
  dft16(xr, xi);
}

// Register-twiddle stage 3: W1024^{(l+64m)k} = (W1024^l * W16^m)^k.
__device__ __forceinline__ void stage3_reg(float* xr, float* xi, int l) {
  float sl, cl;
  __sincosf(-TWOPI * (float)l * (1.0f / 1024.0f), &sl, &cl);
  const float W16mR[4] = {1.f,  0.9238795325f,  0.7071067812f,  0.3826834324f};
  const float W16mI[4] = {0.f, -0.3826834324f, -0.7071067812f, -0.9238795325f};
#pragma unroll
  for (int m = 0; m < 4; ++m) {        // stage 3 (Ns=256, radix-4), in-place
    float ar[4], ai_[4];
#pragma unroll
    for (int k = 0; k < 4; ++k) { ar[k] = xr[m + 4*k]; ai_[k] = xi[m + 4*k]; }
    float w1r, w1i, w2r, w2i, w3r, w3i;
    CMUL(w1r, w1i, cl, sl, W16mR[m], W16mI[m]);  // W1024^{l+64m}
    CMUL(w2r, w2i, w1r, w1i, w1r, w1i);          // ^2
    CMUL(w3r, w3i, w2r, w2i, w1r, w1i);          // ^3
    CMUL(ar[1], ai_[1], ar[1], ai_[1], w1r, w1i);
    CMUL(ar[2], ai_[2], ar[2], ai_[2], w2r, w2i);
    CMUL(ar[3], ai_[3], ar[3], ai_[3], w3r, w3i);
    RADIX4(ar[0],ai_[0], ar[1],ai_[1], ar[2],ai_[2], ar[3],ai_[3],
           xr[m],xi[m], xr[m+4],xi[m+4], xr[m+8],xi[m+8], xr[m+12],xi[m+12]);
  }
}

// f32 1-buffer wave FFT (R12-proven — the precision-safe configuration):
// sequential re/im round-trips through ONE 1088-float buffer (in-order DS
// pipe). Ex2 gather lands at slots xr[m+4k] -> stage 3 exactly in-place.
__device__ __forceinline__ void wave_fft1024_1buf(float* xr, float* xi,
                                                  float* wb, int l) {
  const int base2 = l + (l >> 4);
  const int j2 = l & 15;
  const int ob = 272 * (l >> 4) + j2;
  dft16(xr, xi);                       // stage 1 (Ns=1)
#pragma unroll
  for (int k = 0; k < 16; ++k) wb[17*l + k] = xr[k];
  WBAR();
#pragma unroll
  for (int k = 0; k < 16; ++k) xr[k] = wb[base2 + 68*k];
  WBAR();
#pragma unroll
  for (int k = 0; k < 16; ++k) wb[17*l + k] = xi[k];
  WBAR();
#pragma unroll
  for (int k = 0; k < 16; ++k) xi[k] = wb[base2 + 68*k];
  WBAR();
  stage2_reg(xr, xi, j2);              // stage 2 (Ns=16)
#pragma unroll
  for (int k = 0; k < 16; ++k) wb[ob + 17*k] = xr[k];
  WBAR();
#pragma unroll
  for (int m = 0; m < 4; ++m)
#pragma unroll
    for (int k = 0; k < 4; ++k) xr[m + 4*k] = wb[base2 + 68*m + 272*k];
  WBAR();
#pragma unroll
  for (int k = 0; k < 16; ++k) wb[ob + 17*k] = xi[k];
  WBAR();
#pragma unroll
  for (int m = 0; m < 4; ++m)
#pragma unroll
    for (int k = 0; k < 4; ++k) xi[m + 4*k] = wb[base2 + 68*m + 272*k];
  WBAR();
  stage3_reg(xr, xi, l);
}

// Pass 1 (R12-exact + folded slot init): 8 waves/block, 16 rows, f32 1-buffer
// FFT, Hermitian unpack + transposed staging in two v-halves, XCD swizzle,
// fp16 A (packed at the global write only — the precision-validated point).
// Block 0 initializes the minmax slots (rowfft completes before colfft
// launches; stream order guarantees visibility) — k_init launch deleted.
__global__ __launch_bounds__(512, 6) void k_rowfft(const float* __restrict__ in,
                                                   __half2* __restrict__ A,
                                                   int* __restrict__ slots) {
  __shared__ float lds[8704];          // 8 waves x 1088; overlaid: stg [16][260] x2
  const int t  = threadIdx.x;
  const int w  = t >> 6;               // 0..7
  const int l  = t & 63;
  const int j   = blockIdx.x;
  if (j == 0) {                        // fold slot init (2048 ints, 4 iters)
#pragma unroll
    for (int g = 0; g < 4; ++g) {
      int idx = t + 512 * g;
      slots[idx] = (idx < 1024) ? 0x7F800000 : 0;
    }
  }
  const int q   = j >> 3;
  const int bc  = (j & 7) * 6 + (q >> 6);   // image 0..47 (XCD swizzle)
  const int h0b = (q & 63) << 4;            // 16 rows per block
  const int r0  = h0b + 2 * w;
  float* wb = lds + w * 1088;
  const float* row0 = in + ((size_t)bc << 20) + ((size_t)r0 << 10);
  const float* row1 = row0 + N;
  float xr[16], xi[16];
  const float sgn = (l & 1) ? -1.0f : 1.0f;   // fftshift sign (-1)^h
#pragma unroll
  for (int k = 0; k < 16; ++k) {
    xr[k] =  sgn * row0[l + 64*k];
    xi[k] = -sgn * row1[l + 64*k];
  }
  wave_fft1024_1buf(xr, xi, wb, l);
  // Hermitian unpack A=(P+conj(Q))/2, B=-i(P-conj(Q))/2, Q=Z[(N-i)&1023],
  // staged + written per v-half; Z re-staged per half from register xr/xi.
  float* stre = lds;                   // [16][260]
  float* stim = lds + 4160;            // [16][260]
  const int rr = t & 15, v0 = t >> 4;
  __half2* Abc = A + (size_t)bc * AST;
#pragma unroll
  for (int h = 0; h < 2; ++h) {
    const int slo = (h == 0) ? 0 : 4;
    const int cnt = (h == 0) ? 4 : 5;
    float par[5], pai[5], pbr[5], pbi[5];
    __syncthreads();                   // staging/wb free (prev half fully read)
#pragma unroll
    for (int s = 0; s < 16; ++s) wb[l + 64*s] = xr[s];
    WBAR();
#pragma unroll
    for (int u = 0; u < 5; ++u) {
      if (u < cnt) {
        int s = slo + u;
        int i = l + 64*s;
        if (i <= 512) {
          float qr = wb[(N - i) & (N - 1)];
          par[u] = 0.5f * (xr[s] + qr);
          pbi[u] = 0.5f * (qr - xr[s]);
        }
      }
    }
    WBAR();
#pragma unroll
    for (int s = 0; s < 16; ++s) wb[l + 64*s] = xi[s];
    WBAR();
#pragma unroll
    for (int u = 0; u < 5; ++u) {
      if (u < cnt) {
        int s = slo + u;
        int i = l + 64*s;
        if (i <= 512) {
          float qi = wb[(N - i) & (N - 1)];
          pai[u] = 0.5f * (xi[s] - qi);
          pbr[u] = 0.5f * (xi[s] + qi);
        }
      }
    }
    __syncthreads();                   // all waves done reading Z
#pragma unroll
    for (int u = 0; u < 5; ++u) {
      if (u < cnt) {
        int s = slo + u;
        int i = l + 64*s;
        if (i <= 512) {
          int c = i - 256 * h;
          stre[(2*w)     * 260 + c] = par[u]; stim[(2*w)     * 260 + c] = pai[u];
          stre[(2*w + 1) * 260 + c] = pbr[u]; stim[(2*w + 1) * 260 + c] = pbi[u];
        }
      }
    }
    __syncthreads();
#pragma unroll
    for (int i2 = 0; i2 < 9; ++i2) {
      if (i2 < 8 + h) {
        int v = 256 * h + v0 + 32 * i2;
        if (v <= 512) {
          int c = v - 256 * h;
          Abc[(size_t)v * N + h0b + rr] =
              __floats2half2_rn(stre[rr*260 + c], stim[rr*260 + c]);
        }
      }
    }
  }
}

// Pass 2 (R12-exact): fused column FFT (f32 1-buffer, 17408 B/block -> 8
// blocks/CU) + spec + sliced minmax atomics + 10-tap fused resize.
__global__ __launch_bounds__(256, 8) void k_colfft(const __half2* __restrict__ A,
                                                   float* __restrict__ WSf,
                                                   int* __restrict__ slots) {
  __shared__ float lds[4352];          // 4 waves x 1088
  const int t  = threadIdx.x;
  const int w  = t >> 6;
  const int l  = t & 63;
  const int gw = blockIdx.x * 4 + w;   // 0..24623 == BC*513-1 exactly
  const int bc = gw / 513;
  const int sx = gw - bc * 513;
  const int b  = bc / CH;
  float* wb = lds + w * 1088;
  const __half2* src = A + (size_t)bc * AST + ((size_t)sx << 10);
  float xr[16], xi[16];
#pragma unroll
  for (int k = 0; k < 16; ++k) {
    float2 v = __half22float2(src[l + 64*k]);
    xr[k] = v.x; xi[k] = v.y;
  }
  wave_fft1024_1buf(xr, xi, wb, l);
  float lmin = 3.4e38f, lmax = 0.0f;
#pragma unroll
  for (int s = 0; s < 16; ++s) {
    float sp = __logf(1.0f + sqrtf(xr[s]*xr[s] + xi[s]*xi[s]));
    wb[l + 64*s] = sp;                 // spec plain-indexed in own buffer
    lmin = fminf(lmin, sp); lmax = fmaxf(lmax, sp);
  }
#pragma unroll
  for (int off = 32; off; off >>= 1) {
    lmin = fminf(lmin, __shfl_xor(lmin, off));
    lmax = fmaxf(lmax, __shfl_xor(lmax, off));
  }
  if (l == 0) {                        // spread over 64 slices/image
    atomicMin(&slots[b * 64 + (sx & 63)],        __float_as_int(lmin));
    atomicMax(&slots[1024 + b * 64 + (sx & 63)], __float_as_int(lmax));
  }
  WBAR();
  float* T1 = WSf + T1BASE + (size_t)bc * T1SZ;
  const bool mir = (sx != 0) && (sx != 512);
#pragma unroll
  for (int obk = 0; obk < 4; ++obk) {
    int oh = l + 64 * obk;
    if (oh < OUTHW) {
      float x = ((float)oh + 0.5f) * KSCALE - 0.5f;
      int jlo = (int)ceilf(x - KSCALE);           // unclamped; window < 10 taps
      float ssum = 0.0f, acc = 0.0f, accm = 0.0f;
#pragma unroll
      for (int u = 0; u < 10; ++u) {
        int jj = jlo + u;
        float wgt = 1.0f - fabsf((float)jj - x) * SCALE;
        wgt = fmaxf(wgt, 0.0f);
        bool valid = (jj >= 0) && (jj <= N - 1);
        if (!valid) wgt = 0.0f;
        int ja = valid ? jj : 0;
        ssum += wgt;
        acc  += wgt * wb[ja];
        accm += wgt * wb[(N - ja) & (N - 1)];
      }
      float inv = 1.0f / ssum;
      T1[(size_t)sx * OUTHW + oh] = acc * inv;
      if (mir) T1[(size_t)(N - sx) * OUTHW + oh] = accm * inv;
    }
  }
}

// Pass 3 (R12-exact): contract v + normalization; direct coalesced T1 reads,
// fixed 10-tap unrolled loop, slot min/max reduction merged in.
__global__ __launch_bounds__(256) void k_resize2(const float* __restrict__ WSf,
                                                 const int* __restrict__ slots,
                                                 float* __restrict__ out) {
  __shared__ float s2[2];
  const int ow = blockIdx.x % OUTHW;
  const int bc = blockIdx.x / OUTHW;
  const int b  = bc / CH;
  const int t  = threadIdx.x;
  if (t < 64) {
    int mn = slots[b * 64 + t];
#pragma unroll
    for (int off = 32; off; off >>= 1) mn = min(mn, __shfl_xor(mn, off));
    if (t == 0) s2[0] = __int_as_float(mn);
  } else if (t < 128) {
    int mx = slots[1024 + b * 64 + (t - 64)];
#pragma unroll
    for (int off = 32; off; off >>= 1) mx = max(mx, __shfl_xor(mx, off));
    if (t == 64) s2[1] = __int_as_float(mx);
  }
  __syncthreads();
  if (t >= OUTHW) return;
  const float mn = s2[0];
  const float mx = s2[1];
  const float inv = 1.0f / (mx - mn + 1e-8f);
  const float* T1 = WSf + T1BASE + (size_t)bc * T1SZ;
  float x = ((float)ow + 0.5f) * KSCALE - 0.5f;
  int jlo = (int)ceilf(x - KSCALE);              // unclamped; window < 10 taps
  float ssum = 0.0f, acc = 0.0f;
#pragma unroll
  for (int u = 0; u < 10; ++u) {
    int jj = jlo + u;
    float wv = 1.0f - fabsf((float)jj - x) * SCALE;
    wv = fmaxf(wv, 0.0f);
    bool valid = (jj >= 0) && (jj <= N - 1);
    if (!valid) wv = 0.0f;
    int ja = valid ? jj : 0;                     // row 0 always valid memory
    ssum += wv;
    acc += wv * T1[(size_t)ja * OUTHW + t];      // coalesced 896B per tap row
  }
  float v = acc / ssum;
  out[((size_t)bc * OUTHW + t) * OUTHW + ow] = (v - mn) * inv;
}

extern "C" void kernel_launch(void* const* d_in, const int* in_sizes, int n_in,
                              void* d_out, int out_size, void* d_ws, size_t ws_size,
                              hipStream_t stream) {
  const float* in = (const float*)d_in[0];
  float* out = (float*)d_out;
  __half2* A = (__half2*)d_ws;                 // dense fp16 A region [0, 100.9MB)
  float* WSf = (float*)d_ws;
  int* slots = (int*)(WSf + SLOTBASE);         // [144.9MB, +8KB)

  k_rowfft<<<BC * 64, 512, 0, stream>>>(in, A, slots);
  k_colfft<<<(BC * 513) / 4, 256, 0, stream>>>(A, WSf, slots);
  k_resize2<<<BC * OUTHW, 256, 0, stream>>>(WSf, slots, out);
}

// Round 17
// 399.861 us; speedup vs baseline: 1.0279x; 1.0033x over previous
//
#include <hip/hip_runtime.h>
#include <hip/hip_fp16.h>
#include <math.h>

#define N 1024
#define BATCH 16
#define CH 3
#define BC 48
#define OUTHW 224
#define KSCALE (1024.0f / 224.0f)
#define SCALE  (224.0f / 1024.0f)
// ---- disjoint workspace layout (byte ranges verified non-overlapping) ----
// A   (half2): [0, 100,859,904)                48 x 525,312 half2 (2.101 MB each)
// T1  (float): [100,859,904, 144,900,096)      48 x 229,376 floats
// slots (int): [144,900,096, 144,908,288)      2048 ints
#define AST    525312                        // half2 per image (513*1024), dense
#define T1BASE 25214976                      // float offset of T1 region
#define T1SZ   (OUTHW * N)                   // 229376 floats per bc
#define SLOTBASE 36225024                    // float offset of slots
#define TWOPI 6.283185307179586f
#define WBAR() __builtin_amdgcn_wave_barrier()

// (ar,ai)*(br,bi) -> (dr,di); safe when d aliases a
#define CMUL(dr, di, ar, ai, br, bi) do {                         \
    float _r = (ar) * (br) - (ai) * (bi);                         \
    float _i = (ar) * (bi) + (ai) * (br);                         \
    (dr) = _r; (di) = _i; } while (0)

// forward DFT-4
#define RADIX4(ar,ai,br,bi,cr,ci,dr,di, o0r,o0i,o1r,o1i,o2r,o2i,o3r,o3i) do { \
    float u0r=(ar)+(cr), u0i=(ai)+(ci);                           \
    float u1r=(ar)-(cr), u1i=(ai)-(ci);                           \
    float u2r=(br)+(dr), u2i=(bi)+(di);                           \
    float u3r=(bi)-(di), u3i=(dr)-(br);                           \
    (o0r)=u0r+u2r; (o0i)=u0i+u2i;                                 \
    (o1r)=u1r+u3r; (o1i)=u1i+u3i;                                 \
    (o2r)=u0r-u2r; (o2i)=u0i-u2i;                                 \
    (o3r)=u1r-u3r; (o3i)=u1i-u3i; } while (0)

// In-register natural-order 16-pt forward DFT (Stockham radix-4 x radix-4).
__device__ __forceinline__ void dft16(float* xr, float* xi) {
  const float W16R[4][4] = {
    {1.f, 1.f, 1.f, 1.f},
    {1.f,  0.9238795325f,  0.7071067812f,  0.3826834324f},
    {1.f,  0.7071067812f,  0.0f,          -0.7071067812f},
    {1.f,  0.3826834324f, -0.7071067812f, -0.9238795325f}};
  const float W16I[4][4] = {
    {0.f, 0.f, 0.f, 0.f},
    {0.f, -0.3826834324f, -0.7071067812f, -0.9238795325f},
    {0.f, -0.7071067812f, -1.0f,          -0.7071067812f},
    {0.f, -0.9238795325f, -0.7071067812f,  0.3826834324f}};
  float tr[16], ti[16];
#pragma unroll
  for (int j = 0; j < 4; ++j) {
    RADIX4(xr[j],xi[j], xr[j+4],xi[j+4], xr[j+8],xi[j+8], xr[j+12],xi[j+12],
           tr[4*j],ti[4*j], tr[4*j+1],ti[4*j+1], tr[4*j+2],ti[4*j+2], tr[4*j+3],ti[4*j+3]);
  }
#pragma unroll
  for (int j = 0; j < 4; ++j) {
    float ar[4], ai_[4];
#pragma unroll
    for (int k = 0; k < 4; ++k) {
      if (j == 0 || k == 0) { ar[k] = tr[j+4*k]; ai_[k] = ti[j+4*k]; }
      else CMUL(ar[k], ai_[k], tr[j+4*k], ti[j+4*k], W16R[j][k], W16I[j][k]);
    }
    RADIX4(ar[0],ai_[0], ar[1],ai_[1], ar[2],ai_[2], ar[3],ai_[3],
           xr[j],xi[j], xr[j+4],xi[j+4], xr[j+8],xi[j+8], xr[j+12],xi[j+12]);
  }
}

// Stage 2 with REGISTER twiddles: W256^{j2*k} from one sincos + 14-CMUL
// recurrence (error ~15 ulp, << fp16 A error). No memory traffic.
__device__ __forceinline__ void stage2_reg(float* xr, float* xi, int j2) {
  float s1, c1;
  __sincosf(-TWOPI * (float)j2 * (1.0f / 256.0f), &s1, &c1);
  float wr = c1, wi = s1;
#pragma unroll
  for (int k = 1; k < 16; ++k) {
    CMUL(xr[k], xi[k], xr[k], xi[k], wr, wi);
    if (k < 15) CMUL(wr, wi, wr, wi, c1, s1);   // w^{k+1}
  }
  dft16(xr, xi);
}

// Register-twiddle stage 3: W1024^{(l+64m)k} = (W1024^l * W16^m)^k.
__device__ __forceinline__ void stage3_reg(float* xr, float* xi, int l) {
  float sl, cl;
  __sincosf(-TWOPI * (float)l * (1.0f / 1024.0f), &sl, &cl);
  const float W16mR[4] = {1.f,  0.9238795325f,  0.7071067812f,  0.3826834324f};
  const float W16mI[4] = {0.f, -0.3826834324f, -0.7071067812f, -0.9238795325f};
#pragma unroll
  for (int m = 0; m < 4; ++m) {        // stage 3 (Ns=256, radix-4), in-place
    float ar[4], ai_[4];
#pragma unroll
    for (int k = 0; k < 4; ++k) { ar[k] = xr[m + 4*k]; ai_[k] = xi[m + 4*k]; }
    float w1r, w1i, w2r, w2i, w3r, w3i;
    CMUL(w1r, w1i, cl, sl, W16mR[m], W16mI[m]);  // W1024^{l+64m}
    CMUL(w2r, w2i, w1r, w1i, w1r, w1i);          // ^2
    CMUL(w3r, w3i, w2r, w2i, w1r, w1i);          // ^3
    CMUL(ar[1], ai_[1], ar[1], ai_[1], w1r, w1i);
    CMUL(ar[2], ai_[2], ar[2], ai_[2], w2r, w2i);
    CMUL(ar[3], ai_[3], ar[3], ai_[3], w3r, w3i);
    RADIX4(ar[0],ai_[0], ar[1],ai_[1], ar[2],ai_[2], ar[3],ai_[3],
           xr[m],xi[m], xr[m+4],xi[m+4], xr[m+8],xi[m+8], xr[m+12],xi[m+12]);
  }
}

// f32 1-buffer wave FFT (R12-proven; rowfft control arm).
__device__ __forceinline__ void wave_fft1024_1buf(float* xr, float* xi,
                                                  float* wb, int l) {
  const int base2 = l + (l >> 4);
  const int j2 = l & 15;
  const int ob = 272 * (l >> 4) + j2;
  dft16(xr, xi);                       // stage 1 (Ns=1)
#pragma unroll
  for (int k = 0; k < 16; ++k) wb[17*l + k] = xr[k];
  WBAR();
#pragma unroll
  for (int k = 0; k < 16; ++k) xr[k] = wb[base2 + 68*k];
  WBAR();
#pragma unroll
  for (int k = 0; k < 16; ++k) wb[17*l + k] = xi[k];
  WBAR();
#pragma unroll
  for (int k = 0; k < 16; ++k) xi[k] = wb[base2 + 68*k];
  WBAR();
  stage2_reg(xr, xi, j2);              // stage 2 (Ns=16)
#pragma unroll
  for (int k = 0; k < 16; ++k) wb[ob + 17*k] = xr[k];
  WBAR();
#pragma unroll
  for (int m = 0; m < 4; ++m)
#pragma unroll
    for (int k = 0; k < 4; ++k) xr[m + 4*k] = wb[base2 + 68*m + 272*k];
  WBAR();
#pragma unroll
  for (int k = 0; k < 16; ++k) wb[ob + 17*k] = xi[k];
  WBAR();
#pragma unroll
  for (int m = 0; m < 4; ++m)
#pragma unroll
    for (int k = 0; k < 4; ++k) xi[m + 4*k] = wb[base2 + 68*m + 272*k];
  WBAR();
  stage3_reg(xr, xi, l);
}

// TWO-CHAIN interleaved FFT (R17, colfft only): two independent columns per
// wave through two DISJOINT buffers (R1's failure was ONE shared buffer —
// WAR serialized the chains). Exchange phases of c0/c1 are issue-interleaved;
// each chain's VALU (stage2/3, ~250 inst) covers the other chain's LDS
// round-trip latency. DS ops per column unchanged; per-wave ILP = 2.
__device__ __forceinline__ void wave_fft1024_x2(float* xr0, float* xi0,
                                                float* xr1, float* xi1,
                                                float* wb0, float* wb1, int l) {
  const int base2 = l + (l >> 4);
  const int j2 = l & 15;
  const int ob = 272 * (l >> 4) + j2;
  dft16(xr0, xi0);
  dft16(xr1, xi1);
  // ---- exchange 1, re: issue both writes, then both reads
#pragma unroll
  for (int k = 0; k < 16; ++k) wb0[17*l + k] = xr0[k];
#pragma unroll
  for (int k = 0; k < 16; ++k) wb1[17*l + k] = xr1[k];
  WBAR();
#pragma unroll
  for (int k = 0; k < 16; ++k) xr0[k] = wb0[base2 + 68*k];
#pragma unroll
  for (int k = 0; k < 16; ++k) xr1[k] = wb1[base2 + 68*k];
  WBAR();
  // ---- exchange 1, im
#pragma unroll
  for (int k = 0; k < 16; ++k) wb0[17*l + k] = xi0[k];
#pragma unroll
  for (int k = 0; k < 16; ++k) wb1[17*l + k] = xi1[k];
  WBAR();
#pragma unroll
  for (int k = 0; k < 16; ++k) xi0[k] = wb0[base2 + 68*k];
#pragma unroll
  for (int k = 0; k < 16; ++k) xi1[k] = wb1[base2 + 68*k];
  WBAR();
  // ---- stage 2: c0's VALU covers c1's residual exchange latency & v.v.
  stage2_reg(xr0, xi0, j2);
  stage2_reg(xr1, xi1, j2);
  // ---- exchange 2, re
#pragma unroll
  for (int k = 0; k < 16; ++k) wb0[ob + 17*k] = xr0[k];
#pragma unroll
  for (int k = 0; k < 16; ++k) wb1[ob + 17*k] = xr1[k];
  WBAR();
#pragma unroll
  for (int m = 0; m < 4; ++m)
#pragma unroll
    for (int k = 0; k < 4; ++k) xr0[m + 4*k] = wb0[base2 + 68*m + 272*k];
#pragma unroll
  for (int m = 0; m < 4; ++m)
#pragma unroll
    for (int k = 0; k < 4; ++k) xr1[m + 4*k] = wb1[base2 + 68*m + 272*k];
  WBAR();
  // ---- exchange 2, im
#pragma unroll
  for (int k = 0; k < 16; ++k) wb0[ob + 17*k] = xi0[k];
#pragma unroll
  for (int k = 0; k < 16; ++k) wb1[ob + 17*k] = xi1[k];
  WBAR();
#pragma unroll
  for (int m = 0; m < 4; ++m)
#pragma unroll
    for (int k = 0; k < 4; ++k) xi0[m + 4*k] = wb0[base2 + 68*m + 272*k];
#pragma unroll
  for (int m = 0; m < 4; ++m)
#pragma unroll
    for (int k = 0; k < 4; ++k) xi1[m + 4*k] = wb1[base2 + 68*m + 272*k];
  WBAR();
  stage3_reg(xr0, xi0, l);
  stage3_reg(xr1, xi1, l);
}

// Pass 1 (R16-exact): 8 waves/block, 16 rows, f32 1-buffer FFT, Hermitian
// unpack + transposed staging in two v-halves, XCD swizzle, fp16 A. Block 0
// initializes the minmax slots (k_init launch deleted).
__global__ __launch_bounds__(512, 6) void k_rowfft(const float* __restrict__ in,
                                                   __half2* __restrict__ A,
                                                   int* __restrict__ slots) {
  __shared__ float lds[8704];          // 8 waves x 1088; overlaid: stg [16][260] x2
  const int t  = threadIdx.x;
  const int w  = t >> 6;               // 0..7
  const int l  = t & 63;
  const int j   = blockIdx.x;
  if (j == 0) {                        // fold slot init (2048 ints, 4 iters)
#pragma unroll
    for (int g = 0; g < 4; ++g) {
      int idx = t + 512 * g;
      slots[idx] = (idx < 1024) ? 0x7F800000 : 0;
    }
  }
  const int q   = j >> 3;
  const int bc  = (j & 7) * 6 + (q >> 6);   // image 0..47 (XCD swizzle)
  const int h0b = (q & 63) << 4;            // 16 rows per block
  const int r0  = h0b + 2 * w;
  float* wb = lds + w * 1088;
  const float* row0 = in + ((size_t)bc << 20) + ((size_t)r0 << 10);
  const float* row1 = row0 + N;
  float xr[16], xi[16];
  const float sgn = (l & 1) ? -1.0f : 1.0f;   // fftshift sign (-1)^h
#pragma unroll
  for (int k = 0; k < 16; ++k) {
    xr[k] =  sgn * row0[l + 64*k];
    xi[k] = -sgn * row1[l + 64*k];
  }
  wave_fft1024_1buf(xr, xi, wb, l);
  // Hermitian unpack A=(P+conj(Q))/2, B=-i(P-conj(Q))/2, Q=Z[(N-i)&1023],
  // staged + written per v-half; Z re-staged per half from register xr/xi.
  float* stre = lds;                   // [16][260]
  float* stim = lds + 4160;            // [16][260]
  const int rr = t & 15, v0 = t >> 4;
  __half2* Abc = A + (size_t)bc * AST;
#pragma unroll
  for (int h = 0; h < 2; ++h) {
    const int slo = (h == 0) ? 0 : 4;
    const int cnt = (h == 0) ? 4 : 5;
    float par[5], pai[5], pbr[5], pbi[5];
    __syncthreads();                   // staging/wb free (prev half fully read)
#pragma unroll
    for (int s = 0; s < 16; ++s) wb[l + 64*s] = xr[s];
    WBAR();
#pragma unroll
    for (int u = 0; u < 5; ++u) {
      if (u < cnt) {
        int s = slo + u;
        int i = l + 64*s;
        if (i <= 512) {
          float qr = wb[(N - i) & (N - 1)];
          par[u] = 0.5f * (xr[s] + qr);
          pbi[u] = 0.5f * (qr - xr[s]);
        }
      }
    }
    WBAR();
#pragma unroll
    for (int s = 0; s < 16; ++s) wb[l + 64*s] = xi[s];
    WBAR();
#pragma unroll
    for (int u = 0; u < 5; ++u) {
      if (u < cnt) {
        int s = slo + u;
        int i = l + 64*s;
        if (i <= 512) {
          float qi = wb[(N - i) & (N - 1)];
          pai[u] = 0.5f * (xi[s] - qi);
          pbr[u] = 0.5f * (xi[s] + qi);
        }
      }
    }
    __syncthreads();                   // all waves done using wb as Z
#pragma unroll
    for (int u = 0; u < 5; ++u) {
      if (u < cnt) {
        int s = slo + u;
        int i = l + 64*s;
        if (i <= 512) {
          int c = i - 256 * h;
          stre[(2*w)     * 260 + c] = par[u]; stim[(2*w)     * 260 + c] = pai[u];
          stre[(2*w + 1) * 260 + c] = pbr[u]; stim[(2*w + 1) * 260 + c] = pbi[u];
        }
      }
    }
    __syncthreads();
#pragma unroll
    for (int i2 = 0; i2 < 9; ++i2) {
      if (i2 < 8 + h) {
        int v = 256 * h + v0 + 32 * i2;
        if (v <= 512) {
          int c = v - 256 * h;
          Abc[(size_t)v * N + h0b + rr] =
              __floats2half2_rn(stre[rr*260 + c], stim[rr*260 + c]);
        }
      }
    }
  }
}

// Pass 2 (R17): TWO columns per wave through disjoint buffers. 4 waves/block,
// 8 columns/block, 34816 B LDS -> 4 blocks/CU = 16 waves = 32 resident
// CHAINS/CU (same chain count as R16; isolates ILP-vs-TLP). Spec0 -> wb0,
// spec1 -> wb1; both 10-tap resizes per wave (independent gather chains).
__global__ __launch_bounds__(256, 4) void k_colfft(const __half2* __restrict__ A,
                                                   float* __restrict__ WSf,
                                                   int* __restrict__ slots) {
  __shared__ float lds[8704];          // 4 waves x 2176 (two 1088 buffers each)
  const int t  = threadIdx.x;
  const int w  = t >> 6;
  const int l  = t & 63;
  const int g0 = blockIdx.x * 8 + w * 2;    // 0..24622 even; +1 partner
  const int bc0 = g0 / 513,       sx0 = g0 - bc0 * 513;
  const int bc1 = (g0 + 1) / 513, sx1 = (g0 + 1) - bc1 * 513;
  float* wb0 = lds + w * 2176;
  float* wb1 = wb0 + 1088;
  const __half2* s0 = A + (size_t)bc0 * AST + ((size_t)sx0 << 10);
  const __half2* s1 = A + (size_t)bc1 * AST + ((size_t)sx1 << 10);
  float xr0[16], xi0[16], xr1[16], xi1[16];
#pragma unroll
  for (int k = 0; k < 16; ++k) {
    float2 v = __half22float2(s0[l + 64*k]);
    xr0[k] = v.x; xi0[k] = v.y;
  }
#pragma unroll
  for (int k = 0; k < 16; ++k) {
    float2 v = __half22float2(s1[l + 64*k]);
    xr1[k] = v.x; xi1[k] = v.y;
  }
  wave_fft1024_x2(xr0, xi0, xr1, xi1, wb0, wb1, l);
  // log-magnitude spectra + per-column minmax
  float lmin0 = 3.4e38f, lmax0 = 0.0f, lmin1 = 3.4e38f, lmax1 = 0.0f;
#pragma unroll
  for (int s = 0; s < 16; ++s) {
    float sp0 = __logf(1.0f + sqrtf(xr0[s]*xr0[s] + xi0[s]*xi0[s]));
    float sp1 = __logf(1.0f + sqrtf(xr1[s]*xr1[s] + xi1[s]*xi1[s]));
    wb0[l + 64*s] = sp0;
    wb1[l + 64*s] = sp1;
    lmin0 = fminf(lmin0, sp0); lmax0 = fmaxf(lmax0, sp0);
    lmin1 = fminf(lmin1, sp1); lmax1 = fmaxf(lmax1, sp1);
  }
#pragma unroll
  for (int off = 32; off; off >>= 1) {
    lmin0 = fminf(lmin0, __shfl_xor(lmin0, off));
    lmax0 = fmaxf(lmax0, __shfl_xor(lmax0, off));
    lmin1 = fminf(lmin1, __shfl_xor(lmin1, off));
    lmax1 = fmaxf(lmax1, __shfl_xor(lmax1, off));
  }
  if (l == 0) {
    int b0 = bc0 / CH, b1 = bc1 / CH;
    atomicMin(&slots[b0 * 64 + (sx0 & 63)],        __float_as_int(lmin0));
    atomicMax(&slots[1024 + b0 * 64 + (sx0 & 63)], __float_as_int(lmax0));
    atomicMin(&slots[b1 * 64 + (sx1 & 63)],        __float_as_int(lmin1));
    atomicMax(&slots[1024 + b1 * 64 + (sx1 & 63)], __float_as_int(lmax1));
  }
  WBAR();
  float* T10 = WSf + T1BASE + (size_t)bc0 * T1SZ;
  float* T11 = WSf + T1BASE + (size_t)bc1 * T1SZ;
  const bool mir0 = (sx0 != 0) && (sx0 != 512);
  const bool mir1 = (sx1 != 0) && (sx1 != 512);
#pragma unroll
  for (int obk = 0; obk < 4; ++obk) {
    int oh = l + 64 * obk;
    if (oh < OUTHW) {
      float x = ((float)oh + 0.5f) * KSCALE - 0.5f;
      int jlo = (int)ceilf(x - KSCALE);           // unclamped; window < 10 taps
      float ssum = 0.0f, acc0 = 0.0f, accm0 = 0.0f, acc1 = 0.0f, accm1 = 0.0f;
#pragma unroll
      for (int u = 0; u < 10; ++u) {
        int jj = jlo + u;
        float wgt = 1.0f - fabsf((float)jj - x) * SCALE;
        wgt = fmaxf(wgt, 0.0f);
        bool valid = (jj >= 0) && (jj <= N - 1);
        if (!valid) wgt = 0.0f;
        int ja = valid ? jj : 0;
        int jm = (N - ja) & (N - 1);
        ssum  += wgt;
        acc0  += wgt * wb0[ja];
        accm0 += wgt * wb0[jm];
        acc1  += wgt * wb1[ja];
        accm1 += wgt * wb1[jm];
      }
      float inv = 1.0f / ssum;
      T10[(size_t)sx0 * OUTHW + oh] = acc0 * inv;
      if (mir0) T10[(size_t)(N - sx0) * OUTHW + oh] = accm0 * inv;
      T11[(size_t)sx1 * OUTHW + oh] = acc1 * inv;
      if (mir1) T11[(size_t)(N - sx1) * OUTHW + oh] = accm1 * inv;
    }
  }
}

// Pass 3 (R16-exact): contract v + normalization; direct coalesced T1 reads,
// fixed 10-tap unrolled loop, slot min/max reduction merged in.
__global__ __launch_bounds__(256) void k_resize2(const float* __restrict__ WSf,
                                                 const int* __restrict__ slots,
                                                 float* __restrict__ out) {
  __shared__ float s2[2];
  const int ow = blockIdx.x % OUTHW;
  const int bc = blockIdx.x / OUTHW;
  const int b  = bc / CH;
  const int t  = threadIdx.x;
  if (t < 64) {
    int mn = slots[b * 64 + t];
#pragma unroll
    for (int off = 32; off; off >>= 1) mn = min(mn, __shfl_xor(mn, off));
    if (t == 0) s2[0] = __int_as_float(mn);
  } else if (t < 128) {
    int mx = slots[1024 + b * 64 + (t - 64)];
#pragma unroll
    for (int off = 32; off; off >>= 1) mx = max(mx, __shfl_xor(mx, off));
    if (t == 64) s2[1] = __int_as_float(mx);
  }
  __syncthreads();
  if (t >= OUTHW) return;
  const float mn = s2[0];
  const float mx = s2[1];
  const float inv = 1.0f / (mx - mn + 1e-8f);
  const float* T1 = WSf + T1BASE + (size_t)bc * T1SZ;
  float x = ((float)ow + 0.5f) * KSCALE - 0.5f;
  int jlo = (int)ceilf(x - KSCALE);              // unclamped; window < 10 taps
  float ssum = 0.0f, acc = 0.0f;
#pragma unroll
  for (int u = 0; u < 10; ++u) {
    int jj = jlo + u;
    float wv = 1.0f - fabsf((float)jj - x) * SCALE;
    wv = fmaxf(wv, 0.0f);
    bool valid = (jj >= 0) && (jj <= N - 1);
    if (!valid) wv = 0.0f;
    int ja = valid ? jj : 0;                     // row 0 always valid memory
    ssum += wv;
    acc += wv * T1[(size_t)ja * OUTHW + t];      // coalesced 896B per tap row
  }
  float v = acc / ssum;
  out[((size_t)bc * OUTHW + t) * OUTHW + ow] = (v - mn) * inv;
}

extern "C" void kernel_launch(void* const* d_in, const int* in_sizes, int n_in,
                              void* d_out, int out_size, void* d_ws, size_t ws_size,
                              hipStream_t stream) {
  const float* in = (const float*)d_in[0];
  float* out = (float*)d_out;
  __half2* A = (__half2*)d_ws;                 // dense fp16 A region [0, 100.9MB)
  float* WSf = (float*)d_ws;
  int* slots = (int*)(WSf + SLOTBASE);         // [144.9MB, +8KB)

  k_rowfft<<<BC * 64, 512, 0, stream>>>(in, A, slots);
  k_colfft<<<(BC * 513) / 8, 256, 0, stream>>>(A, WSf, slots);   // 3078 blocks
  k_resize2<<<BC * OUTHW, 256, 0, stream>>>(WSf, slots, out);
}